// Round 1
// baseline (8394.848 us; speedup 1.0000x reference)
//
#include <hip/hip_runtime.h>
#include <cmath>

#define U_N 200000
#define L_N 20000
#define T_N 48
#define A_N 2000
#define D3  32

// ---------------- init: split user_emb into 3 factor buffers + seed output sum
__global__ void k_init_users(const float* __restrict__ ue,
                             float* __restrict__ u_l, float* __restrict__ u_t,
                             float* __restrict__ u_a, float* __restrict__ out_users) {
    int i = blockIdx.x * blockDim.x + threadIdx.x;
    if (i >= U_N * 96) return;
    float v = ue[i];
    out_users[i] = v;                       // initial sum term = user_emb itself
    int u = i / 96;
    int d = i - u * 96;
    if (d < 32)       u_l[u * 32 + d]      = v;
    else if (d < 64)  u_t[u * 32 + d - 32] = v;
    else              u_a[u * 32 + d - 64] = v;
}

// ---------------- COO SpMM, dim-parallel: 32 lanes per nonzero, atomic scatter
__global__ void k_spmm(const int* __restrict__ rows, const int* __restrict__ cols,
                       const float* __restrict__ vals, int nnz,
                       const float* __restrict__ x, float* __restrict__ y) {
    int tid = blockIdx.x * blockDim.x + threadIdx.x;
    int nz = tid >> 5;
    if (nz >= nnz) return;
    int d = tid & 31;
    int r = rows[nz];
    int c = cols[nz];
    float v = vals[nz];
    atomicAdd(&y[r * 32 + d], v * x[c * 32 + d]);
}

// ---------------- SpMM for tiny row count (T=48): LDS accumulate then flush
__global__ void k_spmm_small48(const int* __restrict__ rows, const int* __restrict__ cols,
                               const float* __restrict__ vals, int nnz,
                               const float* __restrict__ x, float* __restrict__ y) {
    __shared__ float acc[T_N * D3];
    for (int i = threadIdx.x; i < T_N * D3; i += blockDim.x) acc[i] = 0.f;
    __syncthreads();
    int d = threadIdx.x & 31;
    int grp = threadIdx.x >> 5;                // 8 groups of 32 lanes
    int per_block = (nnz + gridDim.x - 1) / gridDim.x;
    int start = blockIdx.x * per_block;
    int end = min(nnz, start + per_block);
    for (int nz = start + grp; nz < end; nz += (blockDim.x >> 5)) {
        int r = rows[nz];
        int c = cols[nz];
        atomicAdd(&acc[r * 32 + d], vals[nz] * x[c * 32 + d]);
    }
    __syncthreads();
    for (int i = threadIdx.x; i < T_N * D3; i += blockDim.x) atomicAdd(&y[i], acc[i]);
}

// ---------------- attention fusion over the 4 fused channels
// z layout: 4 slices of [U,32] (slice-major). One user per 32-lane half-wave.
__global__ void k_attn(const float* __restrict__ z, const float* __restrict__ W1,
                       const float* __restrict__ b1, const float* __restrict__ w2,
                       float* __restrict__ u_out, float* __restrict__ out_users, int f) {
    __shared__ float sW[32 * 32];
    __shared__ float sb[32];
    __shared__ float sw2[32];
    for (int i = threadIdx.x; i < 1024; i += blockDim.x) sW[i] = W1[i];
    if (threadIdx.x < 32) { sb[threadIdx.x] = b1[threadIdx.x]; sw2[threadIdx.x] = w2[threadIdx.x]; }
    __syncthreads();

    int half = threadIdx.x >> 5;               // 8 users per 256-thread block
    int j = threadIdx.x & 31;
    int u = blockIdx.x * 8 + half;
    if (u >= U_N) return;

    float zk[4];
#pragma unroll
    for (int k = 0; k < 4; ++k) zk[k] = z[k * (U_N * 32) + u * 32 + j];

    float w[4];
#pragma unroll
    for (int k = 0; k < 4; ++k) {
        float h = sb[j];
#pragma unroll
        for (int i = 0; i < 32; ++i) {
            float zi = __shfl(zk[k], i, 32);
            h += zi * sW[i * 32 + j];
        }
        float p = tanhf(h) * sw2[j];
#pragma unroll
        for (int off = 16; off; off >>= 1) p += __shfl_xor(p, off, 32);
        w[k] = p;                               // all 32 lanes hold the same w_k
    }
    float m = fmaxf(fmaxf(w[0], w[1]), fmaxf(w[2], w[3]));
    float e0 = __expf(w[0] - m), e1 = __expf(w[1] - m), e2 = __expf(w[2] - m), e3 = __expf(w[3] - m);
    float inv = 1.f / (e0 + e1 + e2 + e3);
    float o = (e0 * zk[0] + e1 * zk[1] + e2 * zk[2] + e3 * zk[3]) * inv;
    u_out[u * 32 + j] = o;
    out_users[u * 96 + f * 32 + j] += o;        // accumulate sum for the mean
}

// ---------------- final: divide all sums by 3 (mean over 3 snapshots)
__global__ void k_scale(float* __restrict__ out, int n) {
    int i = blockIdx.x * blockDim.x + threadIdx.x;
    if (i < n) out[i] *= (1.0f / 3.0f);
}

extern "C" void kernel_launch(void* const* d_in, const int* in_sizes, int n_in,
                              void* d_out, int out_size, void* d_ws, size_t ws_size,
                              hipStream_t stream) {
    const float* user_emb = (const float*)d_in[0];
    const float* loc_emb  = (const float*)d_in[1];
    const float* time_emb = (const float*)d_in[2];
    const float* act_emb  = (const float*)d_in[3];
    const float* W1s[3] = {(const float*)d_in[4], (const float*)d_in[7], (const float*)d_in[10]};
    const float* b1s[3] = {(const float*)d_in[5], (const float*)d_in[8], (const float*)d_in[11]};
    const float* w2s[3] = {(const float*)d_in[6], (const float*)d_in[9], (const float*)d_in[12]};

    struct Sp { const int* r; const int* c; const float* v; int n; };
    auto sp = [&](int base) {
        return Sp{(const int*)d_in[base], (const int*)d_in[base + 1],
                  (const float*)d_in[base + 2], in_sizes[base]};
    };
    Sp normL = sp(13), normT = sp(16), normA = sp(19), normLT = sp(22),
       normLA = sp(25), normTA = sp(28), normLTA = sp(31),
       vtoeL = sp(34), vtoeT = sp(37), vtoeA = sp(40);

    // workspace layout (floats): z[4*U*32] | u_l[U*32] | u_t[U*32] | u_a[U*32]
    float* ws = (float*)d_ws;
    float* z = ws;
    float* u[3];
    u[0] = ws + (size_t)4 * U_N * 32;
    u[1] = u[0] + (size_t)U_N * 32;
    u[2] = u[1] + (size_t)U_N * 32;

    float* out       = (float*)d_out;
    float* out_users = out;
    float* out_l     = out + (size_t)U_N * 96;
    float* out_t     = out_l + (size_t)L_N * 32;
    float* out_a     = out_t + (size_t)T_N * 32;

    // ---- init sums with the layer-0 snapshots
    k_init_users<<<(U_N * 96 + 255) / 256, 256, 0, stream>>>(user_emb, u[0], u[1], u[2], out_users);
    hipMemcpyAsync(out_l, loc_emb,  (size_t)L_N * 32 * sizeof(float), hipMemcpyDeviceToDevice, stream);
    hipMemcpyAsync(out_t, time_emb, (size_t)T_N * 32 * sizeof(float), hipMemcpyDeviceToDevice, stream);
    hipMemcpyAsync(out_a, act_emb,  (size_t)A_N * 32 * sizeof(float), hipMemcpyDeviceToDevice, stream);

    const Sp* zmats[3][4] = {
        {&normL, &normLT, &normLA, &normLTA},
        {&normT, &normLT, &normTA, &normLTA},
        {&normA, &normLA, &normTA, &normLTA}};
    Sp vtoe[3] = {vtoeL, vtoeT, vtoeA};
    float* oute[3] = {out_l, out_t, out_a};

    for (int layer = 0; layer < 2; ++layer) {
        for (int f = 0; f < 3; ++f) {
            hipMemsetAsync(z, 0, (size_t)4 * U_N * 32 * sizeof(float), stream);
            for (int k = 0; k < 4; ++k) {
                const Sp& m = *zmats[f][k];
                int thr = m.n * 32;
                k_spmm<<<(thr + 255) / 256, 256, 0, stream>>>(
                    m.r, m.c, m.v, m.n, u[f], z + (size_t)k * U_N * 32);
            }
            // vertex->edge update from the CURRENT u[f] (before attention overwrites it)
            const Sp& vm = vtoe[f];
            if (f == 1) {
                k_spmm_small48<<<256, 256, 0, stream>>>(vm.r, vm.c, vm.v, vm.n, u[f], oute[f]);
            } else {
                int thr = vm.n * 32;
                k_spmm<<<(thr + 255) / 256, 256, 0, stream>>>(vm.r, vm.c, vm.v, vm.n, u[f], oute[f]);
            }
            // attention fusion -> new u[f], accumulated into users sum
            k_attn<<<(U_N + 7) / 8, 256, 0, stream>>>(
                z, W1s[f], b1s[f], w2s[f], u[f], out_users, f);
        }
    }

    int total = U_N * 96 + L_N * 32 + T_N * 32 + A_N * 32;
    k_scale<<<(total + 255) / 256, 256, 0, stream>>>(out, total);
}

// Round 2
// 8361.514 us; speedup vs baseline: 1.0040x; 1.0040x over previous
//
#include <hip/hip_runtime.h>
#include <cmath>

#define U_N 200000
#define L_N 20000
#define T_N 48
#define A_N 2000
#define D3  32

// =====================================================================
// common
// =====================================================================
__global__ void k_init_users(const float* __restrict__ ue,
                             float* __restrict__ u_l, float* __restrict__ u_t,
                             float* __restrict__ u_a, float* __restrict__ out_users) {
    int i = blockIdx.x * blockDim.x + threadIdx.x;
    if (i >= U_N * 96) return;
    float v = ue[i];
    out_users[i] = v;
    int u = i / 96;
    int d = i - u * 96;
    if (d < 32)       u_l[u * 32 + d]      = v;
    else if (d < 64)  u_t[u * 32 + d - 32] = v;
    else              u_a[u * 32 + d - 64] = v;
}

__global__ void k_scale(float* __restrict__ out, int n) {
    int i = blockIdx.x * blockDim.x + threadIdx.x;
    if (i < n) out[i] *= (1.0f / 3.0f);
}

// =====================================================================
// CSR build: histogram -> 3-kernel exclusive scan -> cursor scatter
// =====================================================================
__global__ void k_hist(const int* __restrict__ rows, int nnz, int* __restrict__ cnt) {
    int i = blockIdx.x * blockDim.x + threadIdx.x;
    if (i < nnz) atomicAdd(&cnt[rows[i]], 1);
}

// per-block sums over 1024-element chunks
__global__ void k_block_sums(const int* __restrict__ data, int n, int* __restrict__ bsum) {
    int t = threadIdx.x;
    int g0 = blockIdx.x * 1024 + t * 4;
    int s = 0;
#pragma unroll
    for (int k = 0; k < 4; ++k) if (g0 + k < n) s += data[g0 + k];
#pragma unroll
    for (int off = 32; off; off >>= 1) s += __shfl_down(s, off, 64);
    __shared__ int ws_[4];
    if ((t & 63) == 0) ws_[t >> 6] = s;
    __syncthreads();
    if (t == 0) bsum[blockIdx.x] = ws_[0] + ws_[1] + ws_[2] + ws_[3];
}

// single-block exclusive scan of <=256 block sums; writes grand total to *total_out
__global__ void k_scan_bsums(int* __restrict__ bsum, int nblk, int* __restrict__ total_out) {
    __shared__ int s[256];
    int t = threadIdx.x;
    int v = (t < nblk) ? bsum[t] : 0;
    s[t] = v;
    __syncthreads();
    for (int off = 1; off < 256; off <<= 1) {
        int x = (t >= off) ? s[t - off] : 0;
        __syncthreads();
        s[t] += x;
        __syncthreads();
    }
    if (t < nblk) bsum[t] = s[t] - v;          // exclusive
    if (t == 255) *total_out = s[255];
}

// in-place exclusive scan of each 1024-chunk, adding bsum[block] base
__global__ void k_scan_chunk(int* __restrict__ data, const int* __restrict__ bsum, int n) {
    int t = threadIdx.x;
    int g0 = blockIdx.x * 1024 + t * 4;
    int v0 = 0, v1 = 0, v2 = 0, v3 = 0;
    if (g0 + 0 < n) v0 = data[g0 + 0];
    if (g0 + 1 < n) v1 = data[g0 + 1];
    if (g0 + 2 < n) v2 = data[g0 + 2];
    if (g0 + 3 < n) v3 = data[g0 + 3];
    int local = v0 + v1 + v2 + v3;
    int lane = t & 63, w = t >> 6;
    int inc = local;
#pragma unroll
    for (int off = 1; off < 64; off <<= 1) {
        int o = __shfl_up(inc, off, 64);
        if (lane >= off) inc += o;
    }
    __shared__ int wsum[4];
    if (lane == 63) wsum[w] = inc;
    __syncthreads();
    int wbase = 0;
    for (int i = 0; i < w; ++i) wbase += wsum[i];
    int run = bsum[blockIdx.x] + wbase + (inc - local);
    if (g0 + 0 < n) { data[g0 + 0] = run; run += v0; }
    if (g0 + 1 < n) { data[g0 + 1] = run; run += v1; }
    if (g0 + 2 < n) { data[g0 + 2] = run; run += v2; }
    if (g0 + 3 < n) { data[g0 + 3] = run; run += v3; }
}

// scatter (col,val) pairs into CSR order via per-row cursor
__global__ void k_scatter(const int* __restrict__ rows, const int* __restrict__ cols,
                          const float* __restrict__ vals, int nnz,
                          int* __restrict__ cursor, int2* __restrict__ pk) {
    int i = blockIdx.x * blockDim.x + threadIdx.x;
    if (i >= nnz) return;
    int r = rows[i];
    int p = atomicAdd(&cursor[r], 1);
    pk[p] = make_int2(cols[i], __float_as_int(vals[i]));
}

// =====================================================================
// mega kernel: 4 CSR row-sums (the 4 fused channels) + attention fusion
// one user row per 32-lane group; 8 users per 256-thread block
// =====================================================================
__global__ void k_mega(const int* __restrict__ rp0, const int2* __restrict__ pk0,
                       const int* __restrict__ rp1, const int2* __restrict__ pk1,
                       const int* __restrict__ rp2, const int2* __restrict__ pk2,
                       const int* __restrict__ rp3, const int2* __restrict__ pk3,
                       const float* __restrict__ x,
                       const float* __restrict__ W1, const float* __restrict__ b1,
                       const float* __restrict__ w2,
                       float* __restrict__ u_out, float* __restrict__ out_users, int f) {
    __shared__ float sW[32 * 32];
    __shared__ float sb[32];
    __shared__ float sw2[32];
    for (int i = threadIdx.x; i < 1024; i += blockDim.x) sW[i] = W1[i];
    if (threadIdx.x < 32) { sb[threadIdx.x] = b1[threadIdx.x]; sw2[threadIdx.x] = w2[threadIdx.x]; }
    __syncthreads();

    int grp = threadIdx.x >> 5;
    int lane = threadIdx.x & 31;
    int r = blockIdx.x * 8 + grp;
    if (r >= U_N) return;

    const int*  rps[4] = {rp0, rp1, rp2, rp3};
    const int2* pks[4] = {pk0, pk1, pk2, pk3};
    float zk[4];
#pragma unroll
    for (int ch = 0; ch < 4; ++ch) {
        const int* rp = rps[ch];
        const int2* pk = pks[ch];
        int beg = rp[r], end = rp[r + 1];
        float a = 0.f;
        for (int j = beg; j < end; ++j) {
            int2 e = pk[j];
            a += __int_as_float(e.y) * x[(size_t)e.x * 32 + lane];
        }
        zk[ch] = a;
    }

    float w[4];
#pragma unroll
    for (int k = 0; k < 4; ++k) {
        float h = sb[lane];
#pragma unroll
        for (int i = 0; i < 32; ++i) {
            float zi = __shfl(zk[k], i, 32);
            h += zi * sW[i * 32 + lane];
        }
        float p = tanhf(h) * sw2[lane];
#pragma unroll
        for (int off = 16; off; off >>= 1) p += __shfl_xor(p, off, 32);
        w[k] = p;
    }
    float m = fmaxf(fmaxf(w[0], w[1]), fmaxf(w[2], w[3]));
    float e0 = __expf(w[0] - m), e1 = __expf(w[1] - m), e2 = __expf(w[2] - m), e3 = __expf(w[3] - m);
    float inv = 1.f / (e0 + e1 + e2 + e3);
    float o = (e0 * zk[0] + e1 * zk[1] + e2 * zk[2] + e3 * zk[3]) * inv;
    u_out[(size_t)r * 32 + lane] = o;
    out_users[(size_t)r * 96 + f * 32 + lane] += o;
}

// =====================================================================
// vtoe: row-split CSR spmm -> partials -> reduce (adds into out)
// =====================================================================
__global__ void k_csr_split(const int* __restrict__ rp, const int2* __restrict__ pk,
                            const float* __restrict__ x, float* __restrict__ partial,
                            int n_rows, int S) {
    int gid = (blockIdx.x * blockDim.x + threadIdx.x) >> 5;
    int lane = threadIdx.x & 31;
    if (gid >= n_rows * S) return;
    int r = gid / S, s = gid - r * S;
    int beg = rp[r], end = rp[r + 1], len = end - beg;
    int chunk = (len + S - 1) / S;
    int b = beg + s * chunk;
    int e = min(end, b + chunk);
    float a = 0.f;
    for (int j = b; j < e; ++j) {
        int2 t = pk[j];
        a += __int_as_float(t.y) * x[(size_t)t.x * 32 + lane];
    }
    partial[(size_t)gid * 32 + lane] = a;
}

__global__ void k_reduce_partial(const float* __restrict__ partial, float* __restrict__ out,
                                 int n_rows, int S) {
    int i = blockIdx.x * blockDim.x + threadIdx.x;
    if (i >= n_rows * 32) return;
    int r = i >> 5, lane = i & 31;
    float a = 0.f;
    for (int s = 0; s < S; ++s) a += partial[((size_t)(r * S + s)) * 32 + lane];
    out[i] += a;
}

// =====================================================================
// fallback (round-1 path) kernels
// =====================================================================
__global__ void k_spmm(const int* __restrict__ rows, const int* __restrict__ cols,
                       const float* __restrict__ vals, int nnz,
                       const float* __restrict__ x, float* __restrict__ y) {
    int tid = blockIdx.x * blockDim.x + threadIdx.x;
    int nz = tid >> 5;
    if (nz >= nnz) return;
    int d = tid & 31;
    atomicAdd(&y[(size_t)rows[nz] * 32 + d], vals[nz] * x[(size_t)cols[nz] * 32 + d]);
}

__global__ void k_spmm_small48(const int* __restrict__ rows, const int* __restrict__ cols,
                               const float* __restrict__ vals, int nnz,
                               const float* __restrict__ x, float* __restrict__ y) {
    __shared__ float acc[T_N * D3];
    for (int i = threadIdx.x; i < T_N * D3; i += blockDim.x) acc[i] = 0.f;
    __syncthreads();
    int d = threadIdx.x & 31;
    int grp = threadIdx.x >> 5;
    int per_block = (nnz + gridDim.x - 1) / gridDim.x;
    int start = blockIdx.x * per_block;
    int end = min(nnz, start + per_block);
    for (int nz = start + grp; nz < end; nz += (blockDim.x >> 5))
        atomicAdd(&acc[rows[nz] * 32 + d], vals[nz] * x[(size_t)cols[nz] * 32 + d]);
    __syncthreads();
    for (int i = threadIdx.x; i < T_N * D3; i += blockDim.x) atomicAdd(&y[i], acc[i]);
}

__global__ void k_attn(const float* __restrict__ z, const float* __restrict__ W1,
                       const float* __restrict__ b1, const float* __restrict__ w2,
                       float* __restrict__ u_out, float* __restrict__ out_users, int f) {
    __shared__ float sW[32 * 32];
    __shared__ float sb[32];
    __shared__ float sw2[32];
    for (int i = threadIdx.x; i < 1024; i += blockDim.x) sW[i] = W1[i];
    if (threadIdx.x < 32) { sb[threadIdx.x] = b1[threadIdx.x]; sw2[threadIdx.x] = w2[threadIdx.x]; }
    __syncthreads();
    int half = threadIdx.x >> 5;
    int j = threadIdx.x & 31;
    int u = blockIdx.x * 8 + half;
    if (u >= U_N) return;
    float zk[4];
#pragma unroll
    for (int k = 0; k < 4; ++k) zk[k] = z[(size_t)k * (U_N * 32) + (size_t)u * 32 + j];
    float w[4];
#pragma unroll
    for (int k = 0; k < 4; ++k) {
        float h = sb[j];
#pragma unroll
        for (int i = 0; i < 32; ++i) h += __shfl(zk[k], i, 32) * sW[i * 32 + j];
        float p = tanhf(h) * sw2[j];
#pragma unroll
        for (int off = 16; off; off >>= 1) p += __shfl_xor(p, off, 32);
        w[k] = p;
    }
    float m = fmaxf(fmaxf(w[0], w[1]), fmaxf(w[2], w[3]));
    float e0 = __expf(w[0] - m), e1 = __expf(w[1] - m), e2 = __expf(w[2] - m), e3 = __expf(w[3] - m);
    float inv = 1.f / (e0 + e1 + e2 + e3);
    float o = (e0 * zk[0] + e1 * zk[1] + e2 * zk[2] + e3 * zk[3]) * inv;
    u_out[(size_t)u * 32 + j] = o;
    out_users[(size_t)u * 96 + f * 32 + j] += o;
}

// =====================================================================
// host
// =====================================================================
extern "C" void kernel_launch(void* const* d_in, const int* in_sizes, int n_in,
                              void* d_out, int out_size, void* d_ws, size_t ws_size,
                              hipStream_t stream) {
    const float* user_emb = (const float*)d_in[0];
    const float* loc_emb  = (const float*)d_in[1];
    const float* time_emb = (const float*)d_in[2];
    const float* act_emb  = (const float*)d_in[3];
    const float* W1s[3] = {(const float*)d_in[4], (const float*)d_in[7], (const float*)d_in[10]};
    const float* b1s[3] = {(const float*)d_in[5], (const float*)d_in[8], (const float*)d_in[11]};
    const float* w2s[3] = {(const float*)d_in[6], (const float*)d_in[9], (const float*)d_in[12]};

    struct Mat { const int* r; const int* c; const float* v; int nnz; int nrows; };
    auto mk = [&](int base, int nrows) {
        return Mat{(const int*)d_in[base], (const int*)d_in[base + 1],
                   (const float*)d_in[base + 2], in_sizes[base], nrows};
    };
    // 0..6: U-matrices  7,8,9: vtoeL/T/A
    Mat M[10] = {mk(13, U_N), mk(16, U_N), mk(19, U_N), mk(22, U_N), mk(25, U_N),
                 mk(28, U_N), mk(31, U_N), mk(34, L_N), mk(37, T_N), mk(40, A_N)};

    float* out       = (float*)d_out;
    float* out_users = out;
    float* out_l     = out + (size_t)U_N * 96;
    float* out_t     = out_l + (size_t)L_N * 32;
    float* out_a     = out_t + (size_t)T_N * 32;

    // ---------------- workspace layout (CSR path) ----------------
    auto align256 = [](size_t x) { return (x + 255) & ~(size_t)255; };
    size_t off = 0;
    size_t pk_off[10], rp_off[10];
    for (int m = 0; m < 10; ++m) { pk_off[m] = off; off = align256(off + (size_t)M[m].nnz * 8); }
    for (int m = 0; m < 10; ++m) { rp_off[m] = off; off = align256(off + ((size_t)M[m].nrows + 1) * 4); }
    size_t rp_begin = rp_off[0], rp_end = off;
    size_t cur_off = off;  off = align256(off + ((size_t)U_N + 1) * 4);
    size_t bs_off  = off;  off = align256(off + 256 * 4);
    size_t u_off[2][3];
    for (int b = 0; b < 2; ++b)
        for (int f = 0; f < 3; ++f) { u_off[b][f] = off; off = align256(off + (size_t)U_N * 32 * 4); }
    const int SL = 4, ST = 512, SA = 32;
    size_t part_elems = (size_t)32 * max(max(L_N * SL, T_N * ST), A_N * SA);
    size_t part_off = off; off = align256(off + part_elems * 4);
    size_t NEED = off;

    char* wsb = (char*)d_ws;

    if (ws_size >= NEED) {
        // ================= CSR path =================
        // build all 10 CSRs
        hipMemsetAsync(wsb + rp_begin, 0, rp_end - rp_begin, stream);
        int* cursor = (int*)(wsb + cur_off);
        int* bsum   = (int*)(wsb + bs_off);
        for (int m = 0; m < 10; ++m) {
            int* rp = (int*)(wsb + rp_off[m]);
            int2* pk = (int2*)(wsb + pk_off[m]);
            int n = M[m].nrows, nnz = M[m].nnz;
            k_hist<<<(nnz + 255) / 256, 256, 0, stream>>>(M[m].r, nnz, rp);
            int nblk = (n + 1023) / 1024;
            k_block_sums<<<nblk, 256, 0, stream>>>(rp, n, bsum);
            k_scan_bsums<<<1, 256, 0, stream>>>(bsum, nblk, rp + n);
            k_scan_chunk<<<nblk, 256, 0, stream>>>(rp, bsum, n);
            hipMemcpyAsync(cursor, rp, (size_t)n * 4, hipMemcpyDeviceToDevice, stream);
            k_scatter<<<(nnz + 255) / 256, 256, 0, stream>>>(M[m].r, M[m].c, M[m].v, nnz, cursor, pk);
        }

        // init snapshots
        float* u0[3] = {(float*)(wsb + u_off[0][0]), (float*)(wsb + u_off[0][1]), (float*)(wsb + u_off[0][2])};
        float* u1[3] = {(float*)(wsb + u_off[1][0]), (float*)(wsb + u_off[1][1]), (float*)(wsb + u_off[1][2])};
        k_init_users<<<(U_N * 96 + 255) / 256, 256, 0, stream>>>(user_emb, u0[0], u0[1], u0[2], out_users);
        hipMemcpyAsync(out_l, loc_emb,  (size_t)L_N * 32 * 4, hipMemcpyDeviceToDevice, stream);
        hipMemcpyAsync(out_t, time_emb, (size_t)T_N * 32 * 4, hipMemcpyDeviceToDevice, stream);
        hipMemcpyAsync(out_a, act_emb,  (size_t)A_N * 32 * 4, hipMemcpyDeviceToDevice, stream);

        int chmat[3][4] = {{0, 3, 4, 6}, {1, 3, 5, 6}, {2, 4, 5, 6}};
        int Svt[3] = {SL, ST, SA};
        float* oute[3] = {out_l, out_t, out_a};
        float* partial = (float*)(wsb + part_off);

        for (int layer = 0; layer < 2; ++layer) {
            float** ucur = (layer & 1) ? u1 : u0;
            float** unxt = (layer & 1) ? u0 : u1;
            for (int f = 0; f < 3; ++f) {
                // vertex->edge (reads pre-attention ucur[f])
                Mat& vm = M[7 + f];
                int S = Svt[f];
                int ngrp = vm.nrows * S;
                k_csr_split<<<(ngrp * 32 + 255) / 256, 256, 0, stream>>>(
                    (int*)(wsb + rp_off[7 + f]), (int2*)(wsb + pk_off[7 + f]),
                    ucur[f], partial, vm.nrows, S);
                k_reduce_partial<<<(vm.nrows * 32 + 255) / 256, 256, 0, stream>>>(
                    partial, oute[f], vm.nrows, S);
                // fused 4-channel spmm + attention -> unxt[f]
                int* rpa[4]; int2* pka[4];
                for (int k = 0; k < 4; ++k) {
                    rpa[k] = (int*)(wsb + rp_off[chmat[f][k]]);
                    pka[k] = (int2*)(wsb + pk_off[chmat[f][k]]);
                }
                k_mega<<<(U_N + 7) / 8, 256, 0, stream>>>(
                    rpa[0], pka[0], rpa[1], pka[1], rpa[2], pka[2], rpa[3], pka[3],
                    ucur[f], W1s[f], b1s[f], w2s[f], unxt[f], out_users, f);
            }
        }
    } else {
        // ================= fallback (round-1) path =================
        float* ws = (float*)d_ws;
        float* z = ws;
        float* u[3];
        u[0] = ws + (size_t)4 * U_N * 32;
        u[1] = u[0] + (size_t)U_N * 32;
        u[2] = u[1] + (size_t)U_N * 32;
        k_init_users<<<(U_N * 96 + 255) / 256, 256, 0, stream>>>(user_emb, u[0], u[1], u[2], out_users);
        hipMemcpyAsync(out_l, loc_emb,  (size_t)L_N * 32 * 4, hipMemcpyDeviceToDevice, stream);
        hipMemcpyAsync(out_t, time_emb, (size_t)T_N * 32 * 4, hipMemcpyDeviceToDevice, stream);
        hipMemcpyAsync(out_a, act_emb,  (size_t)A_N * 32 * 4, hipMemcpyDeviceToDevice, stream);
        int chmat[3][4] = {{0, 3, 4, 6}, {1, 3, 5, 6}, {2, 4, 5, 6}};
        float* oute[3] = {out_l, out_t, out_a};
        for (int layer = 0; layer < 2; ++layer) {
            for (int f = 0; f < 3; ++f) {
                hipMemsetAsync(z, 0, (size_t)4 * U_N * 32 * 4, stream);
                for (int k = 0; k < 4; ++k) {
                    Mat& m = M[chmat[f][k]];
                    k_spmm<<<(m.nnz * 32 + 255) / 256, 256, 0, stream>>>(
                        m.r, m.c, m.v, m.nnz, u[f], z + (size_t)k * U_N * 32);
                }
                Mat& vm = M[7 + f];
                if (f == 1)
                    k_spmm_small48<<<256, 256, 0, stream>>>(vm.r, vm.c, vm.v, vm.nnz, u[f], oute[f]);
                else
                    k_spmm<<<(vm.nnz * 32 + 255) / 256, 256, 0, stream>>>(vm.r, vm.c, vm.v, vm.nnz, u[f], oute[f]);
                k_attn<<<(U_N + 7) / 8, 256, 0, stream>>>(z, W1s[f], b1s[f], w2s[f], u[f], out_users, f);
            }
        }
    }

    int total = U_N * 96 + L_N * 32 + T_N * 32 + A_N * 32;
    k_scale<<<(total + 255) / 256, 256, 0, stream>>>(out, total);
}

// Round 3
// 6909.863 us; speedup vs baseline: 1.2149x; 1.2101x over previous
//
#include <hip/hip_runtime.h>
#include <cmath>

#define U_N 200000
#define L_N 20000
#define T_N 48
#define A_N 2000

// =====================================================================
// init / finalize
// =====================================================================
__global__ void k_init_users(const float* __restrict__ ue,
                             float* __restrict__ u_l, float* __restrict__ u_t,
                             float* __restrict__ u_a, float* __restrict__ out_users) {
    int i = blockIdx.x * blockDim.x + threadIdx.x;
    if (i >= U_N * 96) return;
    float v = ue[i];
    out_users[i] = v;
    int u = i / 96;
    int d = i - u * 96;
    if (d < 32)       u_l[u * 32 + d]      = v;
    else if (d < 64)  u_t[u * 32 + d - 32] = v;
    else              u_a[u * 32 + d - 64] = v;
}

__global__ void k_scale(float* __restrict__ out, int n) {
    int i = blockIdx.x * blockDim.x + threadIdx.x;
    if (i < n) out[i] *= (1.0f / 3.0f);
}

// =====================================================================
// CSR build: histogram -> scan -> cursor scatter
// =====================================================================
__global__ void k_hist(const int* __restrict__ rows, int nnz, int* __restrict__ cnt) {
    int i = blockIdx.x * blockDim.x + threadIdx.x;
    if (i < nnz) atomicAdd(&cnt[rows[i]], 1);
}

__global__ void k_block_sums(const int* __restrict__ data, int n, int* __restrict__ bsum) {
    int t = threadIdx.x;
    int g0 = blockIdx.x * 1024 + t * 4;
    int s = 0;
#pragma unroll
    for (int k = 0; k < 4; ++k) if (g0 + k < n) s += data[g0 + k];
#pragma unroll
    for (int off = 32; off; off >>= 1) s += __shfl_down(s, off, 64);
    __shared__ int ws_[4];
    if ((t & 63) == 0) ws_[t >> 6] = s;
    __syncthreads();
    if (t == 0) bsum[blockIdx.x] = ws_[0] + ws_[1] + ws_[2] + ws_[3];
}

__global__ void k_scan_bsums(int* __restrict__ bsum, int nblk, int* __restrict__ total_out) {
    __shared__ int s[256];
    int t = threadIdx.x;
    int v = (t < nblk) ? bsum[t] : 0;
    s[t] = v;
    __syncthreads();
    for (int off = 1; off < 256; off <<= 1) {
        int x = (t >= off) ? s[t - off] : 0;
        __syncthreads();
        s[t] += x;
        __syncthreads();
    }
    if (t < nblk) bsum[t] = s[t] - v;
    if (t == 255) *total_out = s[255];
}

__global__ void k_scan_chunk(int* __restrict__ data, const int* __restrict__ bsum, int n) {
    int t = threadIdx.x;
    int g0 = blockIdx.x * 1024 + t * 4;
    int v0 = 0, v1 = 0, v2 = 0, v3 = 0;
    if (g0 + 0 < n) v0 = data[g0 + 0];
    if (g0 + 1 < n) v1 = data[g0 + 1];
    if (g0 + 2 < n) v2 = data[g0 + 2];
    if (g0 + 3 < n) v3 = data[g0 + 3];
    int local = v0 + v1 + v2 + v3;
    int lane = t & 63, w = t >> 6;
    int inc = local;
#pragma unroll
    for (int off = 1; off < 64; off <<= 1) {
        int o = __shfl_up(inc, off, 64);
        if (lane >= off) inc += o;
    }
    __shared__ int wsum[4];
    if (lane == 63) wsum[w] = inc;
    __syncthreads();
    int wbase = 0;
    for (int i = 0; i < w; ++i) wbase += wsum[i];
    int run = bsum[blockIdx.x] + wbase + (inc - local);
    if (g0 + 0 < n) { data[g0 + 0] = run; run += v0; }
    if (g0 + 1 < n) { data[g0 + 1] = run; run += v1; }
    if (g0 + 2 < n) { data[g0 + 2] = run; run += v2; }
    if (g0 + 3 < n) { data[g0 + 3] = run; run += v3; }
}

__global__ void k_scatter(const int* __restrict__ rows, const int* __restrict__ cols,
                          const float* __restrict__ vals, int nnz,
                          int* __restrict__ cursor, int2* __restrict__ pk) {
    int i = blockIdx.x * blockDim.x + threadIdx.x;
    if (i >= nnz) return;
    int r = rows[i];
    int p = atomicAdd(&cursor[r], 1);
    pk[p] = make_int2(cols[i], __float_as_int(vals[i]));
}

// =====================================================================
// mega: 4 CSR row-sums + attention fusion; one user per 32-lane group
// =====================================================================
__global__ void k_mega(const int* __restrict__ rp0, const int2* __restrict__ pk0,
                       const int* __restrict__ rp1, const int2* __restrict__ pk1,
                       const int* __restrict__ rp2, const int2* __restrict__ pk2,
                       const int* __restrict__ rp3, const int2* __restrict__ pk3,
                       const float* __restrict__ x,
                       const float* __restrict__ W1, const float* __restrict__ b1,
                       const float* __restrict__ w2,
                       float* __restrict__ u_out, float* __restrict__ out_users, int f) {
    __shared__ float sW[32 * 32];
    __shared__ float sb[32];
    __shared__ float sw2[32];
    for (int i = threadIdx.x; i < 1024; i += blockDim.x) sW[i] = W1[i];
    if (threadIdx.x < 32) { sb[threadIdx.x] = b1[threadIdx.x]; sw2[threadIdx.x] = w2[threadIdx.x]; }
    __syncthreads();

    int grp = threadIdx.x >> 5;
    int lane = threadIdx.x & 31;
    int r = blockIdx.x * 8 + grp;
    if (r >= U_N) return;

    const int*  rps[4] = {rp0, rp1, rp2, rp3};
    const int2* pks[4] = {pk0, pk1, pk2, pk3};
    float zk[4];
#pragma unroll
    for (int ch = 0; ch < 4; ++ch) {
        const int* rp = rps[ch];
        const int2* pk = pks[ch];
        int beg = rp[r], end = rp[r + 1];
        float a = 0.f;
        for (int j = beg; j < end; ++j) {
            int2 e = pk[j];
            a += __int_as_float(e.y) * x[(size_t)e.x * 32 + lane];
        }
        zk[ch] = a;
    }

    float w[4];
#pragma unroll
    for (int k = 0; k < 4; ++k) {
        float h = sb[lane];
#pragma unroll
        for (int i = 0; i < 32; ++i) {
            float zi = __shfl(zk[k], i, 32);
            h += zi * sW[i * 32 + lane];
        }
        float p = tanhf(h) * sw2[lane];
#pragma unroll
        for (int off = 16; off; off >>= 1) p += __shfl_xor(p, off, 32);
        w[k] = p;
    }
    float m = fmaxf(fmaxf(w[0], w[1]), fmaxf(w[2], w[3]));
    float e0 = __expf(w[0] - m), e1 = __expf(w[1] - m), e2 = __expf(w[2] - m), e3 = __expf(w[3] - m);
    float inv = 1.f / (e0 + e1 + e2 + e3);
    float o = (e0 * zk[0] + e1 * zk[1] + e2 * zk[2] + e3 * zk[3]) * inv;
    u_out[(size_t)r * 32 + lane] = o;
    out_users[(size_t)r * 96 + f * 32 + lane] += o;
}

// =====================================================================
// vtoe kernels
// =====================================================================
// one row per 32-lane group; adds into out
__global__ void k_csr_pull_add(const int* __restrict__ rp, const int2* __restrict__ pk,
                               const float* __restrict__ x, float* __restrict__ out, int n_rows) {
    int gid = (blockIdx.x * blockDim.x + threadIdx.x) >> 5;
    int lane = threadIdx.x & 31;
    if (gid >= n_rows) return;
    int beg = rp[gid], end = rp[gid + 1];
    float a = 0.f;
    for (int j = beg; j < end; ++j) {
        int2 t = pk[j];
        a += __int_as_float(t.y) * x[(size_t)t.x * 32 + lane];
    }
    out[(size_t)gid * 32 + lane] += a;
}

// split each row into S chunks -> partial, then reduce-add
__global__ void k_csr_split(const int* __restrict__ rp, const int2* __restrict__ pk,
                            const float* __restrict__ x, float* __restrict__ partial,
                            int n_rows, int S) {
    int gid = (blockIdx.x * blockDim.x + threadIdx.x) >> 5;
    int lane = threadIdx.x & 31;
    if (gid >= n_rows * S) return;
    int r = gid / S, s = gid - r * S;
    int beg = rp[r], end = rp[r + 1], len = end - beg;
    int chunk = (len + S - 1) / S;
    int b = beg + s * chunk;
    int e = min(end, b + chunk);
    float a = 0.f;
    for (int j = b; j < e; ++j) {
        int2 t = pk[j];
        a += __int_as_float(t.y) * x[(size_t)t.x * 32 + lane];
    }
    partial[(size_t)gid * 32 + lane] = a;
}

__global__ void k_reduce_partial(const float* __restrict__ partial, float* __restrict__ out,
                                 int n_rows, int S) {
    int i = blockIdx.x * blockDim.x + threadIdx.x;
    if (i >= n_rows * 32) return;
    int r = i >> 5, lane = i & 31;
    float a = 0.f;
    for (int s = 0; s < S; ++s) a += partial[((size_t)(r * S + s)) * 32 + lane];
    out[i] += a;
}

// tiny row-count (T=48): LDS accumulate per block, atomic flush
__global__ void k_spmm_smallT(const int* __restrict__ rows, const int* __restrict__ cols,
                              const float* __restrict__ vals, int nnz,
                              const float* __restrict__ x, float* __restrict__ y) {
    __shared__ float acc[T_N * 32];
    for (int i = threadIdx.x; i < T_N * 32; i += blockDim.x) acc[i] = 0.f;
    __syncthreads();
    int d = threadIdx.x & 31;
    int grp = threadIdx.x >> 5;
    int per_block = (nnz + gridDim.x - 1) / gridDim.x;
    int start = blockIdx.x * per_block;
    int end = min(nnz, start + per_block);
    for (int nz = start + grp; nz < end; nz += (blockDim.x >> 5))
        atomicAdd(&acc[rows[nz] * 32 + d], vals[nz] * x[(size_t)cols[nz] * 32 + d]);
    __syncthreads();
    for (int i = threadIdx.x; i < T_N * 32; i += blockDim.x)
        if (acc[i] != 0.f) atomicAdd(&y[i], acc[i]);
}

// =====================================================================
// fallback (atomic) kernels
// =====================================================================
__global__ void k_spmm(const int* __restrict__ rows, const int* __restrict__ cols,
                       const float* __restrict__ vals, int nnz,
                       const float* __restrict__ x, float* __restrict__ y) {
    int tid = blockIdx.x * blockDim.x + threadIdx.x;
    int nz = tid >> 5;
    if (nz >= nnz) return;
    int d = tid & 31;
    atomicAdd(&y[(size_t)rows[nz] * 32 + d], vals[nz] * x[(size_t)cols[nz] * 32 + d]);
}

__global__ void k_attn(const float* __restrict__ z, const float* __restrict__ W1,
                       const float* __restrict__ b1, const float* __restrict__ w2,
                       float* __restrict__ u_out, float* __restrict__ out_users, int f) {
    __shared__ float sW[32 * 32];
    __shared__ float sb[32];
    __shared__ float sw2[32];
    for (int i = threadIdx.x; i < 1024; i += blockDim.x) sW[i] = W1[i];
    if (threadIdx.x < 32) { sb[threadIdx.x] = b1[threadIdx.x]; sw2[threadIdx.x] = w2[threadIdx.x]; }
    __syncthreads();
    int half = threadIdx.x >> 5;
    int j = threadIdx.x & 31;
    int u = blockIdx.x * 8 + half;
    if (u >= U_N) return;
    float zk[4];
#pragma unroll
    for (int k = 0; k < 4; ++k) zk[k] = z[(size_t)k * (U_N * 32) + (size_t)u * 32 + j];
    float w[4];
#pragma unroll
    for (int k = 0; k < 4; ++k) {
        float h = sb[j];
#pragma unroll
        for (int i = 0; i < 32; ++i) h += __shfl(zk[k], i, 32) * sW[i * 32 + j];
        float p = tanhf(h) * sw2[j];
#pragma unroll
        for (int off = 16; off; off >>= 1) p += __shfl_xor(p, off, 32);
        w[k] = p;
    }
    float m = fmaxf(fmaxf(w[0], w[1]), fmaxf(w[2], w[3]));
    float e0 = __expf(w[0] - m), e1 = __expf(w[1] - m), e2 = __expf(w[2] - m), e3 = __expf(w[3] - m);
    float inv = 1.f / (e0 + e1 + e2 + e3);
    float o = (e0 * zk[0] + e1 * zk[1] + e2 * zk[2] + e3 * zk[3]) * inv;
    u_out[(size_t)u * 32 + j] = o;
    out_users[(size_t)u * 96 + f * 32 + j] += o;
}

// =====================================================================
// host
// =====================================================================
extern "C" void kernel_launch(void* const* d_in, const int* in_sizes, int n_in,
                              void* d_out, int out_size, void* d_ws, size_t ws_size,
                              hipStream_t stream) {
    const float* user_emb = (const float*)d_in[0];
    const float* loc_emb  = (const float*)d_in[1];
    const float* time_emb = (const float*)d_in[2];
    const float* act_emb  = (const float*)d_in[3];
    const float* W1s[3] = {(const float*)d_in[4], (const float*)d_in[7], (const float*)d_in[10]};
    const float* b1s[3] = {(const float*)d_in[5], (const float*)d_in[8], (const float*)d_in[11]};
    const float* w2s[3] = {(const float*)d_in[6], (const float*)d_in[9], (const float*)d_in[12]};

    struct Mat { const int* r; const int* c; const float* v; int nnz; int nrows; };
    auto mk = [&](int base, int nrows) {
        return Mat{(const int*)d_in[base], (const int*)d_in[base + 1],
                   (const float*)d_in[base + 2], in_sizes[base], nrows};
    };
    // 0..6: L,T,A,LT,LA,TA,LTA (rows=U); 7: vtoeL; 8: vtoeT; 9: vtoeA
    Mat M[10] = {mk(13, U_N), mk(16, U_N), mk(19, U_N), mk(22, U_N), mk(25, U_N),
                 mk(28, U_N), mk(31, U_N), mk(34, L_N), mk(37, T_N), mk(40, A_N)};

    float* out       = (float*)d_out;
    float* out_users = out;
    float* out_l     = out + (size_t)U_N * 96;
    float* out_t     = out_l + (size_t)L_N * 32;
    float* out_a     = out_t + (size_t)T_N * 32;

    const int chmat[3][4] = {{0, 3, 4, 6}, {1, 3, 5, 6}, {2, 4, 5, 6}};

    // ------- workspace layout -------
    auto align256 = [](size_t x) { return (x + 255) & ~(size_t)255; };
    char* wsb = (char*)d_ws;
    // Belady pool: 9 matrices (all except vtoeT=8)
    const int NPOOL = 9;
    const int poolM[NPOOL] = {0, 1, 2, 3, 4, 5, 6, 7, 9};

    size_t off = 0;
    size_t ubuf_off[4];
    for (int b = 0; b < 4; ++b) { ubuf_off[b] = off; off = align256(off + (size_t)U_N * 32 * 4); }
    size_t rp_off[10];
    size_t rp_begin = off;
    for (int p = 0; p < NPOOL; ++p) {
        int m = poolM[p];
        rp_off[m] = off;
        off = align256(off + ((size_t)M[m].nrows + 1) * 4);
    }
    size_t rp_total = off - rp_begin;
    size_t cur_off = off;  off = align256(off + ((size_t)U_N + 1) * 4);
    size_t bs_off  = off;  off = align256(off + 1024);
    const int SA = 16;
    size_t part_off = off; off = align256(off + (size_t)A_N * SA * 32 * 4);
    size_t fixed = off;

    size_t max_nnz = 0;
    for (int p = 0; p < NPOOL; ++p) if ((size_t)M[poolM[p]].nnz > max_nnz) max_nnz = M[poolM[p]].nnz;
    size_t slotB = align256(max_nnz * 8);
    int nslot = 0;
    if (ws_size > fixed) {
        size_t avail = ws_size - fixed;
        nslot = (int)(avail / slotB);
        if (nslot > NPOOL) nslot = NPOOL;
    }

    if (nslot >= 4) {
        // ======================= CSR path =======================
        int* cursor = (int*)(wsb + cur_off);
        int* bsum   = (int*)(wsb + bs_off);
        float* partial = (float*)(wsb + part_off);
        size_t slots_off = fixed;
        auto slotPtr = [&](int v) { return (int2*)(wsb + slots_off + (size_t)v * slotB); };
        auto rpPtr = [&](int m) { return (int*)(wsb + rp_off[m]); };

        // ---- build all rp (hist + scan) once per launch
        hipMemsetAsync(wsb + rp_begin, 0, rp_total, stream);
        for (int p = 0; p < NPOOL; ++p) {
            int m = poolM[p];
            int n = M[m].nrows, nnz = M[m].nnz;
            int* rp = rpPtr(m);
            k_hist<<<(nnz + 255) / 256, 256, 0, stream>>>(M[m].r, nnz, rp);
            int nblk = (n + 1023) / 1024;
            k_block_sums<<<nblk, 256, 0, stream>>>(rp, n, bsum);
            k_scan_bsums<<<1, 256, 0, stream>>>(bsum, nblk, rp + n);
            k_scan_chunk<<<nblk, 256, 0, stream>>>(rp, bsum, n);
        }

        // ---- Belady slot scheduler over the known 10-step sequence
        // steps (per layer): {7}, mega_l{0,3,4,6}, mega_t{1,3,5,6}, {9}, mega_a{2,4,5,6}
        const int needs5[5][4] = {{7, -1, -1, -1}, {0, 3, 4, 6}, {1, 3, 5, 6},
                                  {9, -1, -1, -1}, {2, 4, 5, 6}};
        const int NSTEP = 10;
        auto stepNeeds = [&](int s) { return needs5[s % 5]; };
        auto inNeeds = [&](int m, int s) {
            const int* nd = stepNeeds(s);
            for (int j = 0; j < 4; ++j) if (nd[j] == m) return true;
            return false;
        };
        auto nextUse = [&](int m, int s) {
            for (int t = s + 1; t < NSTEP; ++t) if (inNeeds(m, t)) return t;
            return 1 << 28;
        };
        int slotMat[NPOOL]; for (int v = 0; v < NPOOL; ++v) slotMat[v] = -1;
        int matSlot[10];    for (int m = 0; m < 10; ++m) matSlot[m] = -1;

        auto ensure = [&](int s) {
            const int* nd = stepNeeds(s);
            for (int j = 0; j < 4; ++j) {
                int m = nd[j];
                if (m < 0 || matSlot[m] >= 0) continue;
                int best = -1; long bestD = -1;
                for (int v = 0; v < nslot; ++v) {
                    int mm = slotMat[v];
                    if (mm >= 0 && inNeeds(mm, s)) continue;
                    long d = (mm < 0) ? (1L << 40) : (long)nextUse(mm, s);
                    if (d > bestD) { bestD = d; best = v; }
                }
                int mm = slotMat[best];
                if (mm >= 0) matSlot[mm] = -1;
                slotMat[best] = m; matSlot[m] = best;
                hipMemcpyAsync(cursor, rpPtr(m), (size_t)M[m].nrows * 4,
                               hipMemcpyDeviceToDevice, stream);
                k_scatter<<<(M[m].nnz + 255) / 256, 256, 0, stream>>>(
                    M[m].r, M[m].c, M[m].v, M[m].nnz, cursor, slotPtr(matSlot[m]));
            }
        };

        // ---- init snapshots
        float* bufs[4];
        for (int b = 0; b < 4; ++b) bufs[b] = (float*)(wsb + ubuf_off[b]);
        float* ucur[3] = {bufs[0], bufs[1], bufs[2]};
        float* uspare = bufs[3];
        k_init_users<<<(U_N * 96 + 255) / 256, 256, 0, stream>>>(
            user_emb, ucur[0], ucur[1], ucur[2], out_users);
        hipMemcpyAsync(out_l, loc_emb,  (size_t)L_N * 32 * 4, hipMemcpyDeviceToDevice, stream);
        hipMemcpyAsync(out_t, time_emb, (size_t)T_N * 32 * 4, hipMemcpyDeviceToDevice, stream);
        hipMemcpyAsync(out_a, act_emb,  (size_t)A_N * 32 * 4, hipMemcpyDeviceToDevice, stream);

        auto mega = [&](int f) {
            const int* cm = chmat[f];
            k_mega<<<(U_N + 7) / 8, 256, 0, stream>>>(
                rpPtr(cm[0]), slotPtr(matSlot[cm[0]]),
                rpPtr(cm[1]), slotPtr(matSlot[cm[1]]),
                rpPtr(cm[2]), slotPtr(matSlot[cm[2]]),
                rpPtr(cm[3]), slotPtr(matSlot[cm[3]]),
                ucur[f], W1s[f], b1s[f], w2s[f], uspare, out_users, f);
            float* t = ucur[f]; ucur[f] = uspare; uspare = t;
        };

        int s = 0;
        for (int layer = 0; layer < 2; ++layer) {
            // f = 0 (location)
            ensure(s);   // {7} vtoeL
            k_csr_pull_add<<<(L_N * 32 + 255) / 256, 256, 0, stream>>>(
                rpPtr(7), slotPtr(matSlot[7]), ucur[0], out_l, L_N);
            ++s;
            ensure(s);   // mega_l
            mega(0);
            ++s;
            // f = 1 (time): vtoeT via LDS-atomic (reads pre-update ucur[1])
            k_spmm_smallT<<<2048, 256, 0, stream>>>(
                M[8].r, M[8].c, M[8].v, M[8].nnz, ucur[1], out_t);
            ensure(s);   // mega_t
            mega(1);
            ++s;
            // f = 2 (activity)
            ensure(s);   // {9} vtoeA
            k_csr_split<<<(A_N * SA * 32 + 255) / 256, 256, 0, stream>>>(
                rpPtr(9), slotPtr(matSlot[9]), ucur[2], partial, A_N, SA);
            k_reduce_partial<<<(A_N * 32 + 255) / 256, 256, 0, stream>>>(
                partial, out_a, A_N, SA);
            ++s;
            ensure(s);   // mega_a
            mega(2);
            ++s;
        }
    } else {
        // ======================= atomic fallback =======================
        float* ws = (float*)d_ws;
        float* z = ws;
        float* u[3];
        u[0] = ws + (size_t)4 * U_N * 32;
        u[1] = u[0] + (size_t)U_N * 32;
        u[2] = u[1] + (size_t)U_N * 32;
        k_init_users<<<(U_N * 96 + 255) / 256, 256, 0, stream>>>(user_emb, u[0], u[1], u[2], out_users);
        hipMemcpyAsync(out_l, loc_emb,  (size_t)L_N * 32 * 4, hipMemcpyDeviceToDevice, stream);
        hipMemcpyAsync(out_t, time_emb, (size_t)T_N * 32 * 4, hipMemcpyDeviceToDevice, stream);
        hipMemcpyAsync(out_a, act_emb,  (size_t)A_N * 32 * 4, hipMemcpyDeviceToDevice, stream);
        float* oute[3] = {out_l, out_t, out_a};
        for (int layer = 0; layer < 2; ++layer) {
            for (int f = 0; f < 3; ++f) {
                hipMemsetAsync(z, 0, (size_t)4 * U_N * 32 * 4, stream);
                for (int k = 0; k < 4; ++k) {
                    Mat& m = M[chmat[f][k]];
                    k_spmm<<<((size_t)m.nnz * 32 + 255) / 256, 256, 0, stream>>>(
                        m.r, m.c, m.v, m.nnz, u[f], z + (size_t)k * U_N * 32);
                }
                Mat& vm = M[7 + f];
                if (f == 1)
                    k_spmm_smallT<<<2048, 256, 0, stream>>>(vm.r, vm.c, vm.v, vm.nnz, u[f], oute[f]);
                else
                    k_spmm<<<((size_t)vm.nnz * 32 + 255) / 256, 256, 0, stream>>>(
                        vm.r, vm.c, vm.v, vm.nnz, u[f], oute[f]);
                k_attn<<<(U_N + 7) / 8, 256, 0, stream>>>(z, W1s[f], b1s[f], w2s[f], u[f], out_users, f);
            }
        }
    }

    int total = U_N * 96 + L_N * 32 + T_N * 32 + A_N * 32;
    k_scale<<<(total + 255) / 256, 256, 0, stream>>>(out, total);
}

// Round 4
// 5730.537 us; speedup vs baseline: 1.4649x; 1.2058x over previous
//
#include <hip/hip_runtime.h>
#include <cmath>

#define U_N 200000
#define L_N 20000
#define T_N 48
#define A_N 2000

// =====================================================================
// init / finalize
// =====================================================================
__global__ void k_init_users(const float* __restrict__ ue,
                             float* __restrict__ u_l, float* __restrict__ u_t,
                             float* __restrict__ u_a, float* __restrict__ out_users) {
    int i = blockIdx.x * blockDim.x + threadIdx.x;
    if (i >= U_N * 96) return;
    float v = ue[i];
    out_users[i] = v;
    int u = i / 96;
    int d = i - u * 96;
    if (d < 32)       u_l[u * 32 + d]      = v;
    else if (d < 64)  u_t[u * 32 + d - 32] = v;
    else              u_a[u * 32 + d - 64] = v;
}

__global__ void k_scale(float* __restrict__ out, int n) {
    int i = blockIdx.x * blockDim.x + threadIdx.x;
    if (i < n) out[i] *= (1.0f / 3.0f);
}

// =====================================================================
// CSR build: histogram -> scan -> cursor scatter
// =====================================================================
__global__ void k_hist(const int* __restrict__ rows, int nnz, int* __restrict__ cnt) {
    int i = blockIdx.x * blockDim.x + threadIdx.x;
    if (i < nnz) atomicAdd(&cnt[rows[i]], 1);
}

__global__ void k_block_sums(const int* __restrict__ data, int n, int* __restrict__ bsum) {
    int t = threadIdx.x;
    int g0 = blockIdx.x * 1024 + t * 4;
    int s = 0;
#pragma unroll
    for (int k = 0; k < 4; ++k) if (g0 + k < n) s += data[g0 + k];
#pragma unroll
    for (int off = 32; off; off >>= 1) s += __shfl_down(s, off, 64);
    __shared__ int ws_[4];
    if ((t & 63) == 0) ws_[t >> 6] = s;
    __syncthreads();
    if (t == 0) bsum[blockIdx.x] = ws_[0] + ws_[1] + ws_[2] + ws_[3];
}

__global__ void k_scan_bsums(int* __restrict__ bsum, int nblk, int* __restrict__ total_out) {
    __shared__ int s[256];
    int t = threadIdx.x;
    int v = (t < nblk) ? bsum[t] : 0;
    s[t] = v;
    __syncthreads();
    for (int off = 1; off < 256; off <<= 1) {
        int x = (t >= off) ? s[t - off] : 0;
        __syncthreads();
        s[t] += x;
        __syncthreads();
    }
    if (t < nblk) bsum[t] = s[t] - v;
    if (t == 255) *total_out = s[255];
}

__global__ void k_scan_chunk(int* __restrict__ data, const int* __restrict__ bsum, int n) {
    int t = threadIdx.x;
    int g0 = blockIdx.x * 1024 + t * 4;
    int v0 = 0, v1 = 0, v2 = 0, v3 = 0;
    if (g0 + 0 < n) v0 = data[g0 + 0];
    if (g0 + 1 < n) v1 = data[g0 + 1];
    if (g0 + 2 < n) v2 = data[g0 + 2];
    if (g0 + 3 < n) v3 = data[g0 + 3];
    int local = v0 + v1 + v2 + v3;
    int lane = t & 63, w = t >> 6;
    int inc = local;
#pragma unroll
    for (int off = 1; off < 64; off <<= 1) {
        int o = __shfl_up(inc, off, 64);
        if (lane >= off) inc += o;
    }
    __shared__ int wsum[4];
    if (lane == 63) wsum[w] = inc;
    __syncthreads();
    int wbase = 0;
    for (int i = 0; i < w; ++i) wbase += wsum[i];
    int run = bsum[blockIdx.x] + wbase + (inc - local);
    if (g0 + 0 < n) { data[g0 + 0] = run; run += v0; }
    if (g0 + 1 < n) { data[g0 + 1] = run; run += v1; }
    if (g0 + 2 < n) { data[g0 + 2] = run; run += v2; }
    if (g0 + 3 < n) { data[g0 + 3] = run; run += v3; }
}

__global__ void k_scatter(const int* __restrict__ rows, const int* __restrict__ cols,
                          const float* __restrict__ vals, int nnz,
                          int* __restrict__ cursor, int2* __restrict__ pk) {
    int i = blockIdx.x * blockDim.x + threadIdx.x;
    if (i >= nnz) return;
    int r = rows[i];
    int p = atomicAdd(&cursor[r], 1);
    pk[p] = make_int2(cols[i], __float_as_int(vals[i]));
}

// =====================================================================
// mega: 4 CSR row-sums + attention fusion; one user per 32-lane group.
// Gather loop unrolled x4 for memory-level parallelism; pk streamed
// nontemporally (read-once, keep L2 for the x table).
// =====================================================================
__global__ void k_mega(const int* __restrict__ rp0, const long long* __restrict__ pk0,
                       const int* __restrict__ rp1, const long long* __restrict__ pk1,
                       const int* __restrict__ rp2, const long long* __restrict__ pk2,
                       const int* __restrict__ rp3, const long long* __restrict__ pk3,
                       const float* __restrict__ x,
                       const float* __restrict__ W1, const float* __restrict__ b1,
                       const float* __restrict__ w2,
                       float* __restrict__ u_out, float* __restrict__ out_users, int f) {
    __shared__ float sW[32 * 32];
    __shared__ float sb[32];
    __shared__ float sw2[32];
    for (int i = threadIdx.x; i < 1024; i += blockDim.x) sW[i] = W1[i];
    if (threadIdx.x < 32) { sb[threadIdx.x] = b1[threadIdx.x]; sw2[threadIdx.x] = w2[threadIdx.x]; }
    __syncthreads();

    int grp = threadIdx.x >> 5;
    int lane = threadIdx.x & 31;
    int r = blockIdx.x * 8 + grp;
    if (r >= U_N) return;

    const int*       rps[4] = {rp0, rp1, rp2, rp3};
    const long long* pks[4] = {pk0, pk1, pk2, pk3};
    float zk[4];
#pragma unroll 1
    for (int ch = 0; ch < 4; ++ch) {
        const int* rp = rps[ch];
        const long long* pk = pks[ch];
        int j = rp[r], end = rp[r + 1];
        float a = 0.f;
        for (; j + 4 <= end; j += 4) {
            long long e0 = __builtin_nontemporal_load(pk + j);
            long long e1 = __builtin_nontemporal_load(pk + j + 1);
            long long e2 = __builtin_nontemporal_load(pk + j + 2);
            long long e3 = __builtin_nontemporal_load(pk + j + 3);
            float x0 = x[((size_t)(int)e0 << 5) + lane];
            float x1 = x[((size_t)(int)e1 << 5) + lane];
            float x2 = x[((size_t)(int)e2 << 5) + lane];
            float x3 = x[((size_t)(int)e3 << 5) + lane];
            a += __int_as_float((int)(e0 >> 32)) * x0;
            a += __int_as_float((int)(e1 >> 32)) * x1;
            a += __int_as_float((int)(e2 >> 32)) * x2;
            a += __int_as_float((int)(e3 >> 32)) * x3;
        }
        for (; j < end; ++j) {
            long long e = __builtin_nontemporal_load(pk + j);
            a += __int_as_float((int)(e >> 32)) * x[((size_t)(int)e << 5) + lane];
        }
        zk[ch] = a;
    }

    float w[4];
#pragma unroll
    for (int k = 0; k < 4; ++k) {
        float h = sb[lane];
#pragma unroll
        for (int i = 0; i < 32; ++i) {
            float zi = __shfl(zk[k], i, 32);
            h += zi * sW[i * 32 + lane];
        }
        float p = tanhf(h) * sw2[lane];
#pragma unroll
        for (int off = 16; off; off >>= 1) p += __shfl_xor(p, off, 32);
        w[k] = p;
    }
    float m = fmaxf(fmaxf(w[0], w[1]), fmaxf(w[2], w[3]));
    float e0 = __expf(w[0] - m), e1 = __expf(w[1] - m), e2 = __expf(w[2] - m), e3 = __expf(w[3] - m);
    float inv = 1.f / (e0 + e1 + e2 + e3);
    float o = (e0 * zk[0] + e1 * zk[1] + e2 * zk[2] + e3 * zk[3]) * inv;
    u_out[(size_t)r * 32 + lane] = o;
    out_users[(size_t)r * 96 + f * 32 + lane] += o;
}

// =====================================================================
// vtoe kernels (atomic scatter; L/A uncontended enough, T via LDS)
// =====================================================================
__global__ void k_spmm(const int* __restrict__ rows, const int* __restrict__ cols,
                       const float* __restrict__ vals, int nnz,
                       const float* __restrict__ x, float* __restrict__ y) {
    int tid = blockIdx.x * blockDim.x + threadIdx.x;
    int nz = tid >> 5;
    if (nz >= nnz) return;
    int d = tid & 31;
    atomicAdd(&y[(size_t)rows[nz] * 32 + d], vals[nz] * x[(size_t)cols[nz] * 32 + d]);
}

__global__ void k_spmm_smallT(const int* __restrict__ rows, const int* __restrict__ cols,
                              const float* __restrict__ vals, int nnz,
                              const float* __restrict__ x, float* __restrict__ y) {
    __shared__ float acc[T_N * 32];
    for (int i = threadIdx.x; i < T_N * 32; i += blockDim.x) acc[i] = 0.f;
    __syncthreads();
    int d = threadIdx.x & 31;
    int grp = threadIdx.x >> 5;
    int per_block = (nnz + gridDim.x - 1) / gridDim.x;
    int start = blockIdx.x * per_block;
    int end = min(nnz, start + per_block);
    for (int nz = start + grp; nz < end; nz += (blockDim.x >> 5))
        atomicAdd(&acc[rows[nz] * 32 + d], vals[nz] * x[(size_t)cols[nz] * 32 + d]);
    __syncthreads();
    for (int i = threadIdx.x; i < T_N * 32; i += blockDim.x)
        if (acc[i] != 0.f) atomicAdd(&y[i], acc[i]);
}

// =====================================================================
// fallback (atomic z) kernel
// =====================================================================
__global__ void k_attn(const float* __restrict__ z, const float* __restrict__ W1,
                       const float* __restrict__ b1, const float* __restrict__ w2,
                       float* __restrict__ u_out, float* __restrict__ out_users, int f) {
    __shared__ float sW[32 * 32];
    __shared__ float sb[32];
    __shared__ float sw2[32];
    for (int i = threadIdx.x; i < 1024; i += blockDim.x) sW[i] = W1[i];
    if (threadIdx.x < 32) { sb[threadIdx.x] = b1[threadIdx.x]; sw2[threadIdx.x] = w2[threadIdx.x]; }
    __syncthreads();
    int half = threadIdx.x >> 5;
    int j = threadIdx.x & 31;
    int u = blockIdx.x * 8 + half;
    if (u >= U_N) return;
    float zk[4];
#pragma unroll
    for (int k = 0; k < 4; ++k) zk[k] = z[(size_t)k * (U_N * 32) + (size_t)u * 32 + j];
    float w[4];
#pragma unroll
    for (int k = 0; k < 4; ++k) {
        float h = sb[j];
#pragma unroll
        for (int i = 0; i < 32; ++i) h += __shfl(zk[k], i, 32) * sW[i * 32 + j];
        float p = tanhf(h) * sw2[j];
#pragma unroll
        for (int off = 16; off; off >>= 1) p += __shfl_xor(p, off, 32);
        w[k] = p;
    }
    float m = fmaxf(fmaxf(w[0], w[1]), fmaxf(w[2], w[3]));
    float e0 = __expf(w[0] - m), e1 = __expf(w[1] - m), e2 = __expf(w[2] - m), e3 = __expf(w[3] - m);
    float inv = 1.f / (e0 + e1 + e2 + e3);
    float o = (e0 * zk[0] + e1 * zk[1] + e2 * zk[2] + e3 * zk[3]) * inv;
    u_out[(size_t)u * 32 + j] = o;
    out_users[(size_t)u * 96 + f * 32 + j] += o;
}

// =====================================================================
// host
// =====================================================================
extern "C" void kernel_launch(void* const* d_in, const int* in_sizes, int n_in,
                              void* d_out, int out_size, void* d_ws, size_t ws_size,
                              hipStream_t stream) {
    const float* user_emb = (const float*)d_in[0];
    const float* loc_emb  = (const float*)d_in[1];
    const float* time_emb = (const float*)d_in[2];
    const float* act_emb  = (const float*)d_in[3];
    const float* W1s[3] = {(const float*)d_in[4], (const float*)d_in[7], (const float*)d_in[10]};
    const float* b1s[3] = {(const float*)d_in[5], (const float*)d_in[8], (const float*)d_in[11]};
    const float* w2s[3] = {(const float*)d_in[6], (const float*)d_in[9], (const float*)d_in[12]};

    struct Mat { const int* r; const int* c; const float* v; int nnz; int nrows; };
    auto mk = [&](int base, int nrows) {
        return Mat{(const int*)d_in[base], (const int*)d_in[base + 1],
                   (const float*)d_in[base + 2], in_sizes[base], nrows};
    };
    // 0..6: L,T,A,LT,LA,TA,LTA (rows=U); 7: vtoeL; 8: vtoeT; 9: vtoeA
    Mat M[10] = {mk(13, U_N), mk(16, U_N), mk(19, U_N), mk(22, U_N), mk(25, U_N),
                 mk(28, U_N), mk(31, U_N), mk(34, L_N), mk(37, T_N), mk(40, A_N)};

    float* out       = (float*)d_out;
    float* out_users = out;
    float* out_l     = out + (size_t)U_N * 96;
    float* out_t     = out_l + (size_t)L_N * 32;
    float* out_a     = out_t + (size_t)T_N * 32;

    const int chmat[3][4] = {{0, 3, 4, 6}, {1, 3, 5, 6}, {2, 4, 5, 6}};

    // ------- workspace layout -------
    auto align256 = [](size_t x) { return (x + 255) & ~(size_t)255; };
    char* wsb = (char*)d_ws;
    const int NPOOL = 7;                     // the 7 U-matrices only

    size_t off = 0;
    size_t ubuf_off[4];
    for (int b = 0; b < 4; ++b) { ubuf_off[b] = off; off = align256(off + (size_t)U_N * 32 * 4); }
    size_t rp_off[7];
    size_t rp_begin = off;
    for (int m = 0; m < NPOOL; ++m) { rp_off[m] = off; off = align256(off + ((size_t)U_N + 1) * 4); }
    size_t rp_total = off - rp_begin;
    size_t cur_off = off;  off = align256(off + ((size_t)U_N + 1) * 4);
    size_t bs_off  = off;  off = align256(off + 1024);
    size_t fixed = off;

    size_t max_nnz = 0;
    for (int m = 0; m < NPOOL; ++m) if ((size_t)M[m].nnz > max_nnz) max_nnz = M[m].nnz;
    size_t slotB = align256(max_nnz * 8);
    int nslot = 0;
    if (ws_size > fixed) {
        size_t avail = ws_size - fixed;
        nslot = (int)(avail / slotB);
        if (nslot > NPOOL) nslot = NPOOL;
    }

    if (nslot >= 4) {
        // ======================= CSR path, factor-major =======================
        int* cursor = (int*)(wsb + cur_off);
        int* bsum   = (int*)(wsb + bs_off);
        size_t slots_off = fixed;
        auto slotPtr = [&](int v) { return (long long*)(wsb + slots_off + (size_t)v * slotB); };
        auto rpPtr = [&](int m) { return (int*)(wsb + rp_off[m]); };

        // ---- build rp (hist + scan) for the 7 pool matrices
        hipMemsetAsync(wsb + rp_begin, 0, rp_total, stream);
        for (int m = 0; m < NPOOL; ++m) {
            int n = M[m].nrows, nnz = M[m].nnz;
            int* rp = rpPtr(m);
            k_hist<<<(nnz + 255) / 256, 256, 0, stream>>>(M[m].r, nnz, rp);
            int nblk = (n + 1023) / 1024;
            k_block_sums<<<nblk, 256, 0, stream>>>(rp, n, bsum);
            k_scan_bsums<<<1, 256, 0, stream>>>(bsum, nblk, rp + n);
            k_scan_chunk<<<nblk, 256, 0, stream>>>(rp, bsum, n);
        }

        // ---- Belady over the 3-step factor-major sequence (needs = chmat[f])
        auto inNeeds = [&](int m, int s) {
            for (int j = 0; j < 4; ++j) if (chmat[s][j] == m) return true;
            return false;
        };
        auto nextUse = [&](int m, int s) {
            for (int t = s + 1; t < 3; ++t) if (inNeeds(m, t)) return t;
            return 1 << 28;
        };
        int slotMat[7]; for (int v = 0; v < 7; ++v) slotMat[v] = -1;
        int matSlot[7]; for (int m = 0; m < 7; ++m) matSlot[m] = -1;
        auto ensure = [&](int s) {
            for (int j = 0; j < 4; ++j) {
                int m = chmat[s][j];
                if (matSlot[m] >= 0) continue;
                int best = -1; long bestD = -1;
                for (int v = 0; v < nslot; ++v) {
                    int mm = slotMat[v];
                    if (mm >= 0 && inNeeds(mm, s)) continue;
                    long d = (mm < 0) ? (1L << 40) : (long)nextUse(mm, s);
                    if (d > bestD) { bestD = d; best = v; }
                }
                int mm = slotMat[best];
                if (mm >= 0) matSlot[mm] = -1;
                slotMat[best] = m; matSlot[m] = best;
                hipMemcpyAsync(cursor, rpPtr(m), (size_t)M[m].nrows * 4,
                               hipMemcpyDeviceToDevice, stream);
                k_scatter<<<(M[m].nnz + 255) / 256, 256, 0, stream>>>(
                    M[m].r, M[m].c, M[m].v, M[m].nnz, cursor, (int2*)slotPtr(matSlot[m]));
            }
        };

        // ---- init snapshots
        float* bufs[4];
        for (int b = 0; b < 4; ++b) bufs[b] = (float*)(wsb + ubuf_off[b]);
        float* ucur[3] = {bufs[0], bufs[1], bufs[2]};
        float* uspare = bufs[3];
        k_init_users<<<(U_N * 96 + 255) / 256, 256, 0, stream>>>(
            user_emb, ucur[0], ucur[1], ucur[2], out_users);
        hipMemcpyAsync(out_l, loc_emb,  (size_t)L_N * 32 * 4, hipMemcpyDeviceToDevice, stream);
        hipMemcpyAsync(out_t, time_emb, (size_t)T_N * 32 * 4, hipMemcpyDeviceToDevice, stream);
        hipMemcpyAsync(out_a, act_emb,  (size_t)A_N * 32 * 4, hipMemcpyDeviceToDevice, stream);

        float* oute[3] = {out_l, out_t, out_a};

        // ---- factor-major: each factor's matrix set stays resident for both layers
        for (int f = 0; f < 3; ++f) {
            ensure(f);
            const int* cm = chmat[f];
            for (int layer = 0; layer < 2; ++layer) {
                // vertex->edge from pre-attention ucur[f]
                Mat& vm = M[7 + f];
                if (f == 1)
                    k_spmm_smallT<<<2048, 256, 0, stream>>>(
                        vm.r, vm.c, vm.v, vm.nnz, ucur[f], oute[f]);
                else
                    k_spmm<<<((size_t)vm.nnz * 32 + 255) / 256, 256, 0, stream>>>(
                        vm.r, vm.c, vm.v, vm.nnz, ucur[f], oute[f]);
                // fused 4-channel pull-spmm + attention
                k_mega<<<(U_N + 7) / 8, 256, 0, stream>>>(
                    rpPtr(cm[0]), slotPtr(matSlot[cm[0]]),
                    rpPtr(cm[1]), slotPtr(matSlot[cm[1]]),
                    rpPtr(cm[2]), slotPtr(matSlot[cm[2]]),
                    rpPtr(cm[3]), slotPtr(matSlot[cm[3]]),
                    ucur[f], W1s[f], b1s[f], w2s[f], uspare, out_users, f);
                float* t = ucur[f]; ucur[f] = uspare; uspare = t;
            }
        }
    } else {
        // ======================= atomic fallback =======================
        float* ws = (float*)d_ws;
        float* z = ws;
        float* u[3];
        u[0] = ws + (size_t)4 * U_N * 32;
        u[1] = u[0] + (size_t)U_N * 32;
        u[2] = u[1] + (size_t)U_N * 32;
        k_init_users<<<(U_N * 96 + 255) / 256, 256, 0, stream>>>(user_emb, u[0], u[1], u[2], out_users);
        hipMemcpyAsync(out_l, loc_emb,  (size_t)L_N * 32 * 4, hipMemcpyDeviceToDevice, stream);
        hipMemcpyAsync(out_t, time_emb, (size_t)T_N * 32 * 4, hipMemcpyDeviceToDevice, stream);
        hipMemcpyAsync(out_a, act_emb,  (size_t)A_N * 32 * 4, hipMemcpyDeviceToDevice, stream);
        float* oute[3] = {out_l, out_t, out_a};
        for (int layer = 0; layer < 2; ++layer) {
            for (int f = 0; f < 3; ++f) {
                hipMemsetAsync(z, 0, (size_t)4 * U_N * 32 * 4, stream);
                for (int k = 0; k < 4; ++k) {
                    Mat& m = M[chmat[f][k]];
                    k_spmm<<<((size_t)m.nnz * 32 + 255) / 256, 256, 0, stream>>>(
                        m.r, m.c, m.v, m.nnz, u[f], z + (size_t)k * U_N * 32);
                }
                Mat& vm = M[7 + f];
                if (f == 1)
                    k_spmm_smallT<<<2048, 256, 0, stream>>>(vm.r, vm.c, vm.v, vm.nnz, u[f], oute[f]);
                else
                    k_spmm<<<((size_t)vm.nnz * 32 + 255) / 256, 256, 0, stream>>>(
                        vm.r, vm.c, vm.v, vm.nnz, u[f], oute[f]);
                k_attn<<<(U_N + 7) / 8, 256, 0, stream>>>(z, W1s[f], b1s[f], w2s[f], u[f], out_users, f);
            }
        }
    }

    int total = U_N * 96 + L_N * 32 + T_N * 32 + A_N * 32;
    k_scale<<<(total + 255) / 256, 256, 0, stream>>>(out, total);
}